// Round 10
// baseline (264.163 us; speedup 1.0000x reference)
//
#include <hip/hip_runtime.h>
#include <math.h>

// Problem constants (from reference):
constexpr int Bc = 4, Tc = 512, Cc = 768, Hc = 12, HSc = 64;
constexpr int QKVN = 3 * Cc;  // 2304
constexpr double EPSd = 1e-6;

typedef unsigned short u16;
typedef __attribute__((ext_vector_type(8))) short short8;  // 8 bf16 = 4 VGPR
typedef __attribute__((ext_vector_type(4))) float f32x4;

// round-to-nearest-even f32 -> bf16
__device__ __forceinline__ u16 f2bf(float x) {
  unsigned u = __float_as_uint(x);
  return (u16)((u + 0x7FFFu + ((u >> 16) & 1u)) >> 16);
}
__device__ __forceinline__ float bf2f(u16 h) {
  return __uint_as_float((unsigned)h << 16);
}

// async global->LDS, 16B per lane (m104 contract: linear LDS dest, per-lane
// global src carries the bank-rotation). Tracked by vmcnt (m135: in-order —
// vmcnt(N) waits until all but the newest N ops completed).
__device__ __forceinline__ void gload16(const u16* g, u16* l) {
  __builtin_amdgcn_global_load_lds(
      (const __attribute__((address_space(1))) void*)g,
      (__attribute__((address_space(3))) void*)l, 16, 0, 0);
}

#define WAITVM0 asm volatile("s_waitcnt vmcnt(0)" ::: "memory")

// ---------------------------------------------------------------------------
// Elementwise 3-way split: fp32 -> h,m,l bf16 planes (24 mantissa bits total;
// residual ~2^-27|x|). For X (same layout as input).
// ---------------------------------------------------------------------------
__global__ void __launch_bounds__(256) convsplit3(
    const float* __restrict__ in, u16* __restrict__ H, u16* __restrict__ M,
    u16* __restrict__ L) {
  const int i = blockIdx.x * 256 + threadIdx.x;
  const float4 v = ((const float4*)in)[i];
  const float x[4] = {v.x, v.y, v.z, v.w};
  ushort4 hv, mv, lv;
  u16* hp = (u16*)&hv; u16* mp = (u16*)&mv; u16* lp = (u16*)&lv;
#pragma unroll
  for (int c = 0; c < 4; ++c) {
    const u16 h = f2bf(x[c]);
    const float r1 = x[c] - bf2f(h);      // exact
    const u16 m = f2bf(r1);
    const u16 l = f2bf(r1 - bf2f(m));     // r2 exact; l rounds it
    hp[c] = h; mp[c] = m; lp[c] = l;
  }
  ((ushort4*)H)[i] = hv;
  ((ushort4*)M)[i] = mv;
  ((ushort4*)L)[i] = lv;
}

// ---------------------------------------------------------------------------
// Transpose + 3-way split: W [K][Nn] fp32 -> 3 bf16 planes [Nn][K]
// (k contiguous, so GEMM B-fragments are 16B-contiguous).
// ---------------------------------------------------------------------------
__global__ void __launch_bounds__(256) convsplit3_t(
    const float* __restrict__ W, u16* __restrict__ Th, u16* __restrict__ Tm,
    u16* __restrict__ Tl, int K, int Nn) {
  __shared__ float t[64][65];
  const int k0 = blockIdx.x * 64, n0 = blockIdx.y * 64;
#pragma unroll
  for (int u = 0; u < 16; ++u) {
    const int idx = u * 256 + threadIdx.x;
    const int r = idx >> 6, c = idx & 63;
    t[r][c] = W[(size_t)(k0 + r) * Nn + n0 + c];
  }
  __syncthreads();
#pragma unroll
  for (int u = 0; u < 16; ++u) {
    const int idx = u * 256 + threadIdx.x;
    const int n = idx >> 6, k = idx & 63;
    const float x = t[k][n];
    const u16 h = f2bf(x);
    const float r1 = x - bf2f(h);
    const u16 m = f2bf(r1);
    const u16 l = f2bf(r1 - bf2f(m));
    Th[(size_t)(n0 + n) * K + k0 + k] = h;
    Tm[(size_t)(n0 + n) * K + k0 + k] = m;
    Tl[(size_t)(n0 + n) * K + k0 + k] = l;
  }
}

// ---------------------------------------------------------------------------
// Split-bf16 MFMA GEMM, PLANES-parameterized:
//  PLANES=3 (qkv): terms hh+hm+mh+hl+lh+mm -> fp32-equivalent (decisions
//    downstream). Bitwise-identical to R8/R9.
//  PLANES=2 (proj): terms hh+hm+mh (drop mm ~2^-18 rel). Proj feeds NO
//    decisions; error << 1.95e-3 output floor. 32KB LDS -> 5 blk/CU.
// 64x64 tile, 256 thr = 4 waves (32x32 quadrant each, 2x2 frags), BK=32,
// double-buffered, counted-vmcnt pipeline (T4, proven R8): per step
// WAIT vmcnt(2*PLANES) (waits only the older buffer's loads, issued a full
// step earlier) -> s_barrier -> compute -> s_barrier -> stage(next+1).
// NEW (R10): XCD-aware bijective block swizzle (T1): wg=(bid&7)*(nwg/8)+bid/8
// gives each XCD a contiguous column-band -> its B-panels stay L2-resident
// (R9: FETCH 50MB vs 20MB inputs = 2.5x re-stream from L3/HBM; the exposed
// latency at WAITVM exceeded the 1-step cover). nwg%8==0 for both grids.
// ---------------------------------------------------------------------------
template <bool WRITE_PARTIAL, int PLANES>
__global__ void __launch_bounds__(256, 3) gemm_mfma3(
    const u16* __restrict__ A, const u16* __restrict__ B,
    const float* __restrict__ bias, float* __restrict__ outp,
    int N, int kPerSplit, int strideA, int strideB) {
  __shared__ __align__(16) u16 AsF[2][PLANES * 64 * 32];
  __shared__ __align__(16) u16 BsF[2][PLANES * 64 * 32];
  const int tid = threadIdx.x;
  const int wid = tid >> 6;         // 0..3
  const int lane = tid & 63;
  const int lm = lane & 15, kg = lane >> 4;
  const int wr = wid >> 1, wc = wid & 1;   // wave -> 32x32 quadrant
  // XCD swizzle (bijective: nwg = 1152 or 384, both %8 == 0)
  const int nwg = gridDim.x * gridDim.y;
  const int bidl = blockIdx.x + gridDim.x * blockIdx.y;
  const int wg = (bidl & 7) * (nwg >> 3) + (bidl >> 3);
  const int rb = (wg % gridDim.x) * 64;
  const int cb = (wg / gridDim.x) * 64;
  const int kBeg = blockIdx.z * kPerSplit;

  // staging geometry: thread -> (row, chunk-in-row); 256 thr cover 64 rows
  const int trow = tid >> 2;          // 0..63
  const int tc4 = tid & 3;            // 16B chunk in 64B row
  const int krot = ((tc4 - (trow >> 1)) & 3) * 8;   // rotation, global side
  const int sLds = tid * 8;                         // LDS elems = tid*16B
  int aOff = (rb + trow) * 768 + kBeg + krot;       // elements
  int bOff = (cb + trow) * 768 + kBeg + krot;

  f32x4 acc[2][2];
#pragma unroll
  for (int mf = 0; mf < 2; ++mf)
#pragma unroll
    for (int nf = 0; nf < 2; ++nf) acc[mf][nf] = (f32x4){0.f, 0.f, 0.f, 0.f};

  const int nIter = kPerSplit / 32;            // 24 (qkv) or 8 (proj); even
  const int ckA = ((kg + (lm >> 1)) & 3) * 8;  // frag-read chunk rotation

  // counted wait: older buffer's 2*PLANES loads landed; newer stay in flight
  auto waitN = [&]() {
    if constexpr (PLANES == 3) {
      asm volatile("s_waitcnt vmcnt(6)" ::: "memory");
    } else {
      asm volatile("s_waitcnt vmcnt(4)" ::: "memory");
    }
  };
  // issue one K-slice's 2*PLANES async loads (per wave) into buffer `buf`
  auto stage = [&](int buf) {
#pragma unroll
    for (int p = 0; p < PLANES; ++p) {
      gload16(A + (size_t)p * strideA + aOff, &AsF[buf][p * 2048 + sLds]);
      gload16(B + (size_t)p * strideB + bOff, &BsF[buf][p * 2048 + sLds]);
    }
    aOff += 32; bOff += 32;
  };
  // fragment reads + MFMAs from buffer `buf`
  auto compute = [&](int buf) {
    short8 ah[2], am[2], al[2];
#pragma unroll
    for (int mf = 0; mf < 2; ++mf) {
      const int ro = (wr * 32 + mf * 16 + lm) * 32 + ckA;
      ah[mf] = *(const short8*)&AsF[buf][ro];
      am[mf] = *(const short8*)&AsF[buf][2048 + ro];
      if constexpr (PLANES == 3) al[mf] = *(const short8*)&AsF[buf][4096 + ro];
    }
#pragma unroll
    for (int nf = 0; nf < 2; ++nf) {
      const int co = (wc * 32 + nf * 16 + lm) * 32 + ckA;
      const short8 bh = *(const short8*)&BsF[buf][co];
      const short8 bm = *(const short8*)&BsF[buf][2048 + co];
      short8 bl;
      if constexpr (PLANES == 3) bl = *(const short8*)&BsF[buf][4096 + co];
#pragma unroll
      for (int mf = 0; mf < 2; ++mf) {
        if constexpr (PLANES == 3) {
          acc[mf][nf] = __builtin_amdgcn_mfma_f32_16x16x32_bf16(
              al[mf], bh, acc[mf][nf], 0, 0, 0);
          acc[mf][nf] = __builtin_amdgcn_mfma_f32_16x16x32_bf16(
              ah[mf], bl, acc[mf][nf], 0, 0, 0);
          acc[mf][nf] = __builtin_amdgcn_mfma_f32_16x16x32_bf16(
              am[mf], bm, acc[mf][nf], 0, 0, 0);
        }
        acc[mf][nf] = __builtin_amdgcn_mfma_f32_16x16x32_bf16(
            am[mf], bh, acc[mf][nf], 0, 0, 0);
        acc[mf][nf] = __builtin_amdgcn_mfma_f32_16x16x32_bf16(
            ah[mf], bm, acc[mf][nf], 0, 0, 0);
        acc[mf][nf] = __builtin_amdgcn_mfma_f32_16x16x32_bf16(
            ah[mf], bh, acc[mf][nf], 0, 0, 0);
      }
    }
  };

  stage(0);            // k-slice 0 in flight (per wave)
  stage(1);            // k-slice 1 in flight
  for (int t = 0; t < nIter; t += 2) {
    // ---- even step: buffer 0, k-slice t ----
    if (t + 1 < nIter) { waitN(); } else { WAITVM0; }   // slice t landed
    __builtin_amdgcn_s_barrier();                       // publish all quarters
    compute(0);
    __builtin_amdgcn_s_barrier();                       // readers done
    if (t + 2 < nIter) stage(0);                        // issue slice t+2
    // ---- odd step: buffer 1, k-slice t+1 ----
    if (t + 2 < nIter) { waitN(); } else { WAITVM0; }   // slice t+1 landed
    __builtin_amdgcn_s_barrier();
    compute(1);
    __builtin_amdgcn_s_barrier();
    if (t + 3 < nIter) stage(1);                        // issue slice t+3
  }

  // epilogue: C/D layout col = lane&15, row = (lane>>4)*4 + reg  [m89/m91]
  const int colb = cb + wc * 32 + lm;
  if (WRITE_PARTIAL) {
    float* Pp = outp + (size_t)blockIdx.z * 2048 * N;
#pragma unroll
    for (int mf = 0; mf < 2; ++mf)
#pragma unroll
      for (int r2 = 0; r2 < 4; ++r2) {
        float* orow =
            Pp + (size_t)(rb + wr * 32 + mf * 16 + kg * 4 + r2) * N + colb;
        orow[0]  = acc[mf][0][r2];
        orow[16] = acc[mf][1][r2];
      }
  } else {
    const float bb0 = bias[colb], bb1 = bias[colb + 16];
#pragma unroll
    for (int mf = 0; mf < 2; ++mf)
#pragma unroll
      for (int r2 = 0; r2 < 4; ++r2) {
        float* orow =
            outp + (size_t)(rb + wr * 32 + mf * 16 + kg * 4 + r2) * N + colb;
        orow[0]  = acc[mf][0][r2] + bb0;
        orow[16] = acc[mf][1][r2] + bb1;
      }
  }
}

// ---------------------------------------------------------------------------
// out = sum_ks P[ks] + bias (fixed order -> deterministic). float4 vectorized.
// ---------------------------------------------------------------------------
__global__ void __launch_bounds__(256) reduce_bias_kernel(
    const float* __restrict__ P, const float* __restrict__ bias,
    float* __restrict__ outp, int MN, int N, int KS) {
  const int idx4 = (blockIdx.x * 256 + threadIdx.x) * 4;
  float4 acc = *(const float4*)&P[idx4];
  for (int ks = 1; ks < KS; ++ks) {
    const float4 p = *(const float4*)&P[(size_t)ks * MN + idx4];
    acc.x += p.x; acc.y += p.y; acc.z += p.z; acc.w += p.w;
  }
  const int col = idx4 % N;
  const float4 b4 = *(const float4*)&bias[col];
  acc.x += b4.x; acc.y += b4.y; acc.z += b4.z; acc.w += b4.w;
  *(float4*)&outp[idx4] = acc;
}

// ---------------------------------------------------------------------------
// S[bh][i][j] = q_i . k_j (fp32). LOWER-TRIANGLE TILES ONLY; j>i masked in
// topk. 64x64x64 tile, 4x4 register tile, operands transposed [d][tok] in LDS.
// ---------------------------------------------------------------------------
__global__ void __launch_bounds__(256) sims_kernel(
    const float* __restrict__ qkv, float* __restrict__ S) {
  const int bh = blockIdx.y;
  const int b = bh / Hc, h = bh % Hc;
  int it = 0;
  {
    const int t = blockIdx.x;
    while ((it + 1) * (it + 2) / 2 <= t) ++it;
  }
  const int jt = blockIdx.x - it * (it + 1) / 2;
  const int tid = threadIdx.x;
  const int tx = tid & 15, ty = tid >> 4;
  __shared__ float Qs[HSc][68];
  __shared__ float Ks[HSc][68];
  const float* base = qkv + (size_t)b * Tc * QKVN + h * HSc;
  {
    const int row = tid >> 2;
    const int d0 = (tid & 3) * 16;
    const float* qrow = base + (size_t)(it * 64 + row) * QKVN;
    const float* krow = base + (size_t)(jt * 64 + row) * QKVN + Cc;
#pragma unroll
    for (int u = 0; u < 4; ++u) {
      const float4 q4 = *(const float4*)&qrow[d0 + u * 4];
      const float4 k4 = *(const float4*)&krow[d0 + u * 4];
      Qs[d0 + u * 4 + 0][row] = q4.x; Qs[d0 + u * 4 + 1][row] = q4.y;
      Qs[d0 + u * 4 + 2][row] = q4.z; Qs[d0 + u * 4 + 3][row] = q4.w;
      Ks[d0 + u * 4 + 0][row] = k4.x; Ks[d0 + u * 4 + 1][row] = k4.y;
      Ks[d0 + u * 4 + 2][row] = k4.z; Ks[d0 + u * 4 + 3][row] = k4.w;
    }
  }
  __syncthreads();
  float acc[4][4];
#pragma unroll
  for (int m = 0; m < 4; ++m)
#pragma unroll
    for (int n = 0; n < 4; ++n) acc[m][n] = 0.0f;
#pragma unroll 4
  for (int d = 0; d < HSc; ++d) {
    const float4 a4 = *(const float4*)&Qs[d][ty * 4];
    const float4 b4 = *(const float4*)&Ks[d][tx * 4];
    const float a[4] = {a4.x, a4.y, a4.z, a4.w};
    const float bv[4] = {b4.x, b4.y, b4.z, b4.w};
#pragma unroll
    for (int m = 0; m < 4; ++m)
#pragma unroll
      for (int n = 0; n < 4; ++n) acc[m][n] += a[m] * bv[n];
  }
  float* Shead = S + (size_t)bh * Tc * Tc;
#pragma unroll
  for (int m = 0; m < 4; ++m) {
    const int i = it * 64 + ty * 4 + m;
    float4 o4 = {acc[m][0], acc[m][1], acc[m][2], acc[m][3]};
    *(float4*)&Shead[(size_t)i * Tc + jt * 64 + tx * 4] = o4;
  }
}

// ---------------------------------------------------------------------------
// Top-16 per token row, one full wave per token. Exact jax.lax.top_k
// semantics. Sort-once + 32-bit tournament (R9, proven). NEW (R10): i is
// wave-uniform -> lanes with lane*8 > i skip the S load entirely (their keys
// were 0 anyway): halves S traffic (50->25MB) and key-build VALU. Exact.
// ---------------------------------------------------------------------------
__global__ void __launch_bounds__(256) topk_kernel(
    const float* __restrict__ S, int* __restrict__ topidx,
    unsigned* __restrict__ availB) {
  const int tid = threadIdx.x;
  const int wv = tid >> 6, lane = tid & 63;
  const int tok = blockIdx.x * 4 + wv;  // bh*512 + i
  const int i = tok & (Tc - 1);
  const float4* Sq = reinterpret_cast<const float4*>(S + (size_t)tok * Tc);
  unsigned long long key[8];
#pragma unroll
  for (int r = 0; r < 2; ++r) {
    const int jb = lane * 8 + r * 4;
    if (jb <= i) {  // causal truncation: skip loads entirely beyond i
      const float4 v4 = Sq[lane * 2 + r];
      const float vv[4] = {v4.x, v4.y, v4.z, v4.w};
#pragma unroll
      for (int c = 0; c < 4; ++c) {
        const int j = jb + c;
        const unsigned u = __float_as_uint(vv[c]);
        const unsigned s = (u & 0x80000000u) ? ~u : (u | 0x80000000u);
        key[r * 4 + c] = (j <= i)
            ? (((unsigned long long)s << 32) | (unsigned)(511 - j))
            : 0ull;
      }
    } else {
      key[r * 4 + 0] = 0ull; key[r * 4 + 1] = 0ull;
      key[r * 4 + 2] = 0ull; key[r * 4 + 3] = 0ull;
    }
  }
  // Batcher odd-even mergesort, 8 elems, descending (19 CE, static indices)
#define CE8(a, b)                                                   \
  {                                                                 \
    const unsigned long long lo_ = key[a] < key[b] ? key[a] : key[b]; \
    const unsigned long long hi_ = key[a] < key[b] ? key[b] : key[a]; \
    key[a] = hi_; key[b] = lo_;                                     \
  }
  CE8(0, 1) CE8(2, 3) CE8(0, 2) CE8(1, 3) CE8(1, 2)   // sort4 {0..3}
  CE8(4, 5) CE8(6, 7) CE8(4, 6) CE8(5, 7) CE8(5, 6)   // sort4 {4..7}
  CE8(0, 4) CE8(1, 5) CE8(2, 6) CE8(3, 7)             // odd-even merge
  CE8(2, 4) CE8(3, 5)
  CE8(1, 2) CE8(3, 4) CE8(5, 6)
#undef CE8

  unsigned avail = 0;
#pragma unroll
  for (int m = 0; m < 16; ++m) {
    unsigned g = (unsigned)(key[0] >> 32);  // my head's value part
    const unsigned myhi = g;
#pragma unroll
    for (int msk = 1; msk <= 32; msk <<= 1) {
      const unsigned o = __shfl_xor(g, msk);
      g = o > g ? o : g;
    }
    // ties (equal float value): lowest lane wins == lowest j (exact jax)
    const unsigned long long ball = __ballot(myhi == g);
    const int winner = __ffsll((unsigned long long)ball) - 1;
    const unsigned lo = __shfl((unsigned)key[0], winner);
    const int j = 511 - (int)lo;
    if (lane == 0) topidx[(size_t)tok * 16 + m] = j & 511;
    if (g > 0x007FFFFFu && j != i) avail |= (1u << m);
    if (lane == winner) {  // pop my sorted list (static register shift)
      key[0] = key[1]; key[1] = key[2]; key[2] = key[3]; key[3] = key[4];
      key[4] = key[5]; key[5] = key[6]; key[6] = key[7]; key[7] = 0ull;
    }
  }
  if (lane == 0) availB[tok] = avail;
}

// ---------------------------------------------------------------------------
// Greedy DPP selection, TWO tokens per wave (lanes 0-31 / 32-63), 2 lanes per
// candidate (32 dims each). LOG-FREE scoring (R4, proven). Output y as TWO
// bf16 planes (h,m — proj is now 2-plane; l plane dropped).
// ---------------------------------------------------------------------------
__global__ void __launch_bounds__(256, 4) select_kernel(
    const float* __restrict__ qkv, const int* __restrict__ topidx,
    const unsigned* __restrict__ availB, u16* __restrict__ yh,
    u16* __restrict__ ym) {
  const int tid = threadIdx.x;
  const int wv = tid >> 6, lane = tid & 63;
  const int half = lane >> 5;       // which token of the wave's pair
  const int l32 = lane & 31;
  const int m = l32 >> 1;           // candidate 0..15
  const int q = l32 & 1;            // 32-dim half of the 64-dim head
  const int hbase = half << 5;      // shfl base for own half

  const int tok = blockIdx.x * 8 + wv * 2 + half;  // bh*512 + i
  const int bh = tok >> 9;
  const int i = tok & (Tc - 1);
  const int b = bh / Hc;
  const int h = bh % Hc;

  const float* base = qkv + (size_t)b * Tc * QKVN + h * HSc;
  const float* kbase = base + Cc;
  const float* vbase = base + 2 * Cc;

  const int tidx = topidx[(size_t)tok * 16 + m];  // pair-uniform
  unsigned avail = availB[tok];                   // half-uniform

  // gather my candidate's 32-dim slice + k_i's slice into registers
  float kreg[32], kireg[32];
  {
    const float* kc = kbase + (size_t)tidx * QKVN + q * 32;
    const float* ki = kbase + (size_t)i * QKVN + q * 32;
#pragma unroll
    for (int u = 0; u < 8; ++u) {
      const float4 c4 = *(const float4*)&kc[u * 4];
      const float4 i4 = *(const float4*)&ki[u * 4];
      kreg[u * 4 + 0] = c4.x; kreg[u * 4 + 1] = c4.y;
      kreg[u * 4 + 2] = c4.z; kreg[u * 4 + 3] = c4.w;
      kireg[u * 4 + 0] = i4.x; kireg[u * 4 + 1] = i4.y;
      kireg[u * 4 + 2] = i4.z; kireg[u * 4 + 3] = i4.w;
    }
  }
  // fp32 partial dots + pair reduce (shfl_xor 1)
  float cnorm_f = 0.0f, c0_f = 0.0f, kii_f = 0.0f;
#pragma unroll
  for (int e = 0; e < 32; ++e) {
    cnorm_f += kreg[e] * kreg[e];
    c0_f += kreg[e] * kireg[e];
    kii_f += kireg[e] * kireg[e];
  }
  cnorm_f += __shfl_xor(cnorm_f, 1);
  c0_f += __shfl_xor(c0_f, 1);
  kii_f += __shfl_xor(kii_f, 1);

  const double kii = (double)kii_f;
  double z[8];
#pragma unroll
  for (int t = 0; t < 8; ++t) z[t] = 0.0;
  z[0] = (double)c0_f / sqrt(kii);
  double schur = (double)cnorm_f - z[0] * z[0];
  double detS = kii;     // half-uniform
  double Dprev = 0.0;    // accepted D (it=0 bypasses the compare)
  int count = 1;
  int sel[8];
  sel[0] = i;
#pragma unroll
  for (int a = 1; a < 8; ++a) sel[a] = 0;
  bool hdone = false;

  // greedy loop: decisions half-uniform; state updates predicated
#pragma unroll
  for (int it = 0; it < 7; ++it) {
    const double D = detS * schur + EPSd;  // per candidate
    const bool act = ((avail >> m) & 1u) != 0;
    // argmin key: nonpos/NaN D (score NaN/+inf) -> -INF (wins, tie lowest m);
    // unavailable -> +INF (loses)
    const bool bad = !(D > 0.0);
    double dkey = act ? (bad ? -INFINITY : D) : INFINITY;
    int bm = m;
#pragma unroll
    for (int msk = 2; msk <= 16; msk <<= 1) {  // keys pair-replicated
      const double ok2 = __shfl_xor(dkey, msk);
      const int om = __shfl_xor(bm, msk);
      const bool t2 = (ok2 < dkey) || (ok2 == dkey && om < bm);
      dkey = t2 ? ok2 : dkey;
      bm = t2 ? om : bm;
    }
    const double Dbest = __shfl(D, hbase | (bm * 2));  // raw winner D
    bool acc_ok;
    if (it == 0) {
      acc_ok = true;  // MIN_SIZE forces first accept (when avail != 0)
    } else {
      // Dbest^(it+1) < Dprev^(it+2), guarded for nonpos/NaN (-> reject,
      // matching NaN-score semantics of the log form)
      double pA = Dbest, pB = Dprev;
#pragma unroll
      for (int j = 0; j < it; ++j) pA *= Dbest;
#pragma unroll
      for (int j = 0; j < it + 1; ++j) pB *= Dprev;
      acc_ok = ((avail >> bm) & 1u) && (Dbest >= 0.0) && (Dprev >= 0.0) &&
               (pA < pB);
    }
    const bool X = !hdone && (avail != 0u) && acc_ok;
    hdone = hdone || !X;
    if (X) {  // half-uniform branch; shfl sources stay within own half
      // cp = k_c . k_best over this lane's 32 dims
      float cp_f = 0.0f;
#pragma unroll
      for (int e = 0; e < 32; ++e) {
        const float kb = __shfl(kreg[e], hbase | (bm * 2) | q);
        cp_f += kreg[e] * kb;
      }
      cp_f += __shfl_xor(cp_f, 1);
      const double schur_b = __shfl(schur, hbase | (bm * 2));
      double sum = 0.0;
#pragma unroll
      for (int t = 0; t <= it; ++t) {
        const double zbt = __shfl(z[t], hbase | (bm * 2));
        sum += z[t] * zbt;
      }
      const double znew = ((double)cp_f - sum) / sqrt(schur_b);
      z[it + 1] = znew;
      schur -= znew * znew;
      detS *= schur_b;
      Dprev = Dbest;
      avail &= ~(1u << bm);
      ++count;
      sel[it + 1] = __shfl(tidx, hbase | (bm * 2));
    }
    if (__all(hdone)) break;
  }

  // output = mean of selected v rows; each lane handles dims l32 and l32+32
  double acc0 = 0.0, acc1 = 0.0;
#pragma unroll
  for (int a = 0; a < 8; ++a)
    if (a < count) {
      const float* vrow = vbase + (size_t)sel[a] * QKVN;
      acc0 += (double)vrow[l32];
      acc1 += (double)vrow[l32 + 32];
    }
  const float v0 = (float)(acc0 / (double)count);
  const float v1 = (float)(acc1 / (double)count);
  const size_t yidx = (((size_t)b * Tc + i) * Hc + h) * HSc + l32;
  {
    const u16 hv = f2bf(v0);
    yh[yidx] = hv; ym[yidx] = f2bf(v0 - bf2f(hv));
  }
  {
    const u16 hv = f2bf(v1);
    yh[yidx + 32] = hv; ym[yidx + 32] = f2bf(v1 - bf2f(hv));
  }
}

// ---------------------------------------------------------------------------
extern "C" void kernel_launch(void* const* d_in, const int* in_sizes, int n_in,
                              void* d_out, int out_size, void* d_ws, size_t ws_size,
                              hipStream_t stream) {
  (void)in_sizes; (void)n_in; (void)out_size; (void)ws_size;
  const float* x  = (const float*)d_in[0];
  const float* Wa = (const float*)d_in[1];
  const float* ba = (const float*)d_in[2];
  const float* Wp = (const float*)d_in[3];
  const float* bp = (const float*)d_in[4];
  float* out = (float*)d_out;

  constexpr size_t XPLANE = (size_t)Bc * Tc * Cc;      // 1,572,864 elems
  constexpr size_t WAPLANE = (size_t)QKVN * Cc;        // 1,769,472
  constexpr size_t WPPLANE = (size_t)Cc * Cc;          //   589,824

  // Workspace layout (~70.9 MB; region B 50.33 MB time-multiplexed):
  float* qkv = (float*)d_ws;                            // 18.87 MB fp32
  int* topidx = (int*)(qkv + (size_t)Bc * Tc * QKVN);   // 1.57 MB
  unsigned* availB = (unsigned*)(topidx + (size_t)Bc * Hc * Tc * 16);  // 98 KB
  float* regionB = (float*)(availB + (size_t)Bc * Hc * Tc);
  //   phase 1 (pre-sims): X planes (9.44 MB) + W_attn planes (10.6 MB)
  //   phase 2 (sims..topk): S (50.33 MB)
  //   phase 3 (post-topk): Pproj (18.87) + Wp planes (3.54) + y planes (6.3)
  float* S = regionB;
  float* Pproj = regionB;
  u16* Xh = (u16*)regionB;
  u16* Wath = Xh + 3 * XPLANE;
  u16* Wpth = (u16*)(regionB + (size_t)3 * 2048 * Cc);  // past Pproj
  u16* yhp = Wpth + 3 * WPPLANE;                        // past Wp planes

  const int MNproj = Bc * Tc * Cc;   // 1,572,864

  // 1) split X and W_attn into 3 bf16 planes each (W transposed -> [N][K])
  hipLaunchKernelGGL(convsplit3, dim3(1536), dim3(256), 0, stream,
                     x, Xh, Xh + XPLANE, Xh + 2 * XPLANE);
  hipLaunchKernelGGL(convsplit3_t, dim3(12, 36), dim3(256), 0, stream,
                     Wa, Wath, Wath + WAPLANE, Wath + 2 * WAPLANE, Cc, QKVN);
  // 2) qkv = x @ W_attn + b_attn via 3-plane split-bf16 MFMA + XCD swizzle
  hipLaunchKernelGGL((gemm_mfma3<false, 3>), dim3(32, QKVN / 64, 1),
                     dim3(256), 0, stream, Xh, Wath, ba, qkv, QKVN, Cc,
                     (int)XPLANE, (int)WAPLANE);
  // 3) S = Q K^T per head, lower-triangle tiles only (overwrites planes; OK)
  hipLaunchKernelGGL(sims_kernel, dim3(36, Bc * Hc), dim3(256), 0,
                     stream, qkv, S);
  // 4) top-16 per token (sort-once tournament + causal-truncated loads)
  hipLaunchKernelGGL(topk_kernel, dim3(Bc * Hc * Tc / 4), dim3(256), 0,
                     stream, S, topidx, availB);
  // 5) greedy DPP, 2 tokens/wave; writes y as 2 bf16 planes (h,m)
  hipLaunchKernelGGL(select_kernel, dim3(Bc * Hc * Tc / 8), dim3(256), 0,
                     stream, qkv, topidx, availB, yhp, yhp + XPLANE);
  // 6) split W_proj (only h,m planes consumed by 2-plane proj)
  hipLaunchKernelGGL(convsplit3_t, dim3(12, 12), dim3(256), 0, stream,
                     Wp, Wpth, Wpth + WPPLANE, Wpth + 2 * WPPLANE, Cc, Cc);
  // 7) proj partials via 2-PLANE split (no decisions downstream; err ~2^-17)
  hipLaunchKernelGGL((gemm_mfma3<true, 2>), dim3(32, Cc / 64, 3), dim3(256),
                     0, stream, yhp, Wpth, nullptr, Pproj, Cc, 256,
                     (int)XPLANE, (int)WPPLANE);
  hipLaunchKernelGGL(reduce_bias_kernel, dim3(MNproj / 1024), dim3(256), 0,
                     stream, Pproj, bp, out, MNproj, Cc, 3);
}

// Round 11
// 251.253 us; speedup vs baseline: 1.0514x; 1.0514x over previous
//
#include <hip/hip_runtime.h>
#include <math.h>

// Problem constants (from reference):
constexpr int Bc = 4, Tc = 512, Cc = 768, Hc = 12, HSc = 64;
constexpr int QKVN = 3 * Cc;  // 2304
constexpr double EPSd = 1e-6;

typedef unsigned short u16;
typedef __attribute__((ext_vector_type(8))) short short8;  // 8 bf16 = 4 VGPR
typedef __attribute__((ext_vector_type(4))) float f32x4;

// round-to-nearest-even f32 -> bf16
__device__ __forceinline__ u16 f2bf(float x) {
  unsigned u = __float_as_uint(x);
  return (u16)((u + 0x7FFFu + ((u >> 16) & 1u)) >> 16);
}
__device__ __forceinline__ float bf2f(u16 h) {
  return __uint_as_float((unsigned)h << 16);
}

// async global->LDS, 16B per lane (m104 contract: linear LDS dest, per-lane
// global src carries the bank-rotation). Tracked by vmcnt (m135: in-order —
// vmcnt(N) waits until all but the newest N ops completed).
__device__ __forceinline__ void gload16(const u16* g, u16* l) {
  __builtin_amdgcn_global_load_lds(
      (const __attribute__((address_space(1))) void*)g,
      (__attribute__((address_space(3))) void*)l, 16, 0, 0);
}

#define WAITVM0 asm volatile("s_waitcnt vmcnt(0)" ::: "memory")

// ---------------------------------------------------------------------------
// Elementwise 3-way split: fp32 -> h,m,l bf16 planes (24 mantissa bits total;
// residual ~2^-27|x|). For X (same layout as input).
// ---------------------------------------------------------------------------
__global__ void __launch_bounds__(256) convsplit3(
    const float* __restrict__ in, u16* __restrict__ H, u16* __restrict__ M,
    u16* __restrict__ L) {
  const int i = blockIdx.x * 256 + threadIdx.x;
  const float4 v = ((const float4*)in)[i];
  const float x[4] = {v.x, v.y, v.z, v.w};
  ushort4 hv, mv, lv;
  u16* hp = (u16*)&hv; u16* mp = (u16*)&mv; u16* lp = (u16*)&lv;
#pragma unroll
  for (int c = 0; c < 4; ++c) {
    const u16 h = f2bf(x[c]);
    const float r1 = x[c] - bf2f(h);      // exact
    const u16 m = f2bf(r1);
    const u16 l = f2bf(r1 - bf2f(m));     // r2 exact; l rounds it
    hp[c] = h; mp[c] = m; lp[c] = l;
  }
  ((ushort4*)H)[i] = hv;
  ((ushort4*)M)[i] = mv;
  ((ushort4*)L)[i] = lv;
}

// ---------------------------------------------------------------------------
// Transpose + 3-way split: W [K][Nn] fp32 -> 3 bf16 planes [Nn][K]
// (k contiguous, so GEMM B-fragments are 16B-contiguous).
// ---------------------------------------------------------------------------
__global__ void __launch_bounds__(256) convsplit3_t(
    const float* __restrict__ W, u16* __restrict__ Th, u16* __restrict__ Tm,
    u16* __restrict__ Tl, int K, int Nn) {
  __shared__ float t[64][65];
  const int k0 = blockIdx.x * 64, n0 = blockIdx.y * 64;
#pragma unroll
  for (int u = 0; u < 16; ++u) {
    const int idx = u * 256 + threadIdx.x;
    const int r = idx >> 6, c = idx & 63;
    t[r][c] = W[(size_t)(k0 + r) * Nn + n0 + c];
  }
  __syncthreads();
#pragma unroll
  for (int u = 0; u < 16; ++u) {
    const int idx = u * 256 + threadIdx.x;
    const int n = idx >> 6, k = idx & 63;
    const float x = t[k][n];
    const u16 h = f2bf(x);
    const float r1 = x - bf2f(h);
    const u16 m = f2bf(r1);
    const u16 l = f2bf(r1 - bf2f(m));
    Th[(size_t)(n0 + n) * K + k0 + k] = h;
    Tm[(size_t)(n0 + n) * K + k0 + k] = m;
    Tl[(size_t)(n0 + n) * K + k0 + k] = l;
  }
}

// ---------------------------------------------------------------------------
// Split-bf16 MFMA GEMM, PLANES-parameterized:
//  PLANES=3 (qkv): terms hh+hm+mh+hl+lh+mm -> fp32-equivalent (decisions
//    downstream). Bitwise-identical to R8/R9.
//  PLANES=2 (proj): terms hh+hm+mh (drop mm ~2^-18 rel). Proj feeds NO
//    decisions; error << 1.95e-3 output floor. 32KB LDS -> 5 blk/CU.
// 64x64 tile, 256 thr = 4 waves (32x32 quadrant each, 2x2 frags), BK=32,
// double-buffered, counted-vmcnt pipeline (T4, proven R8): per step
// WAIT vmcnt(2*PLANES) (waits only the older buffer's loads, issued a full
// step earlier) -> s_barrier -> compute -> s_barrier -> stage(next+1).
// R10 ERRATUM: XCD column-band swizzle REVERTED — it doubled L2 misses
// (FETCH 50->94.5MB, qkv 62.7->70.9us). The DEFAULT round-robin mapping
// already gives each XCD only 4 A-row-panels (1.15MB, L2-resident); the
// swizzle traded that for 32 A-panels/XCD (9.2MB, thrashes 4MB L2).
// Identity tile mapping restored (R9-proven).
// ---------------------------------------------------------------------------
template <bool WRITE_PARTIAL, int PLANES>
__global__ void __launch_bounds__(256, 3) gemm_mfma3(
    const u16* __restrict__ A, const u16* __restrict__ B,
    const float* __restrict__ bias, float* __restrict__ outp,
    int N, int kPerSplit, int strideA, int strideB) {
  __shared__ __align__(16) u16 AsF[2][PLANES * 64 * 32];
  __shared__ __align__(16) u16 BsF[2][PLANES * 64 * 32];
  const int tid = threadIdx.x;
  const int wid = tid >> 6;         // 0..3
  const int lane = tid & 63;
  const int lm = lane & 15, kg = lane >> 4;
  const int wr = wid >> 1, wc = wid & 1;   // wave -> 32x32 quadrant
  const int rb = blockIdx.x * 64;
  const int cb = blockIdx.y * 64;
  const int kBeg = blockIdx.z * kPerSplit;

  // staging geometry: thread -> (row, chunk-in-row); 256 thr cover 64 rows
  const int trow = tid >> 2;          // 0..63
  const int tc4 = tid & 3;            // 16B chunk in 64B row
  const int krot = ((tc4 - (trow >> 1)) & 3) * 8;   // rotation, global side
  const int sLds = tid * 8;                         // LDS elems = tid*16B
  int aOff = (rb + trow) * 768 + kBeg + krot;       // elements
  int bOff = (cb + trow) * 768 + kBeg + krot;

  f32x4 acc[2][2];
#pragma unroll
  for (int mf = 0; mf < 2; ++mf)
#pragma unroll
    for (int nf = 0; nf < 2; ++nf) acc[mf][nf] = (f32x4){0.f, 0.f, 0.f, 0.f};

  const int nIter = kPerSplit / 32;            // 24 (qkv) or 8 (proj); even
  const int ckA = ((kg + (lm >> 1)) & 3) * 8;  // frag-read chunk rotation

  // counted wait: older buffer's 2*PLANES loads landed; newer stay in flight
  auto waitN = [&]() {
    if constexpr (PLANES == 3) {
      asm volatile("s_waitcnt vmcnt(6)" ::: "memory");
    } else {
      asm volatile("s_waitcnt vmcnt(4)" ::: "memory");
    }
  };
  // issue one K-slice's 2*PLANES async loads (per wave) into buffer `buf`
  auto stage = [&](int buf) {
#pragma unroll
    for (int p = 0; p < PLANES; ++p) {
      gload16(A + (size_t)p * strideA + aOff, &AsF[buf][p * 2048 + sLds]);
      gload16(B + (size_t)p * strideB + bOff, &BsF[buf][p * 2048 + sLds]);
    }
    aOff += 32; bOff += 32;
  };
  // fragment reads + MFMAs from buffer `buf`
  auto compute = [&](int buf) {
    short8 ah[2], am[2], al[2];
#pragma unroll
    for (int mf = 0; mf < 2; ++mf) {
      const int ro = (wr * 32 + mf * 16 + lm) * 32 + ckA;
      ah[mf] = *(const short8*)&AsF[buf][ro];
      am[mf] = *(const short8*)&AsF[buf][2048 + ro];
      if constexpr (PLANES == 3) al[mf] = *(const short8*)&AsF[buf][4096 + ro];
    }
#pragma unroll
    for (int nf = 0; nf < 2; ++nf) {
      const int co = (wc * 32 + nf * 16 + lm) * 32 + ckA;
      const short8 bh = *(const short8*)&BsF[buf][co];
      const short8 bm = *(const short8*)&BsF[buf][2048 + co];
      short8 bl;
      if constexpr (PLANES == 3) bl = *(const short8*)&BsF[buf][4096 + co];
#pragma unroll
      for (int mf = 0; mf < 2; ++mf) {
        if constexpr (PLANES == 3) {
          acc[mf][nf] = __builtin_amdgcn_mfma_f32_16x16x32_bf16(
              al[mf], bh, acc[mf][nf], 0, 0, 0);
          acc[mf][nf] = __builtin_amdgcn_mfma_f32_16x16x32_bf16(
              ah[mf], bl, acc[mf][nf], 0, 0, 0);
          acc[mf][nf] = __builtin_amdgcn_mfma_f32_16x16x32_bf16(
              am[mf], bm, acc[mf][nf], 0, 0, 0);
        }
        acc[mf][nf] = __builtin_amdgcn_mfma_f32_16x16x32_bf16(
            am[mf], bh, acc[mf][nf], 0, 0, 0);
        acc[mf][nf] = __builtin_amdgcn_mfma_f32_16x16x32_bf16(
            ah[mf], bm, acc[mf][nf], 0, 0, 0);
        acc[mf][nf] = __builtin_amdgcn_mfma_f32_16x16x32_bf16(
            ah[mf], bh, acc[mf][nf], 0, 0, 0);
      }
    }
  };

  stage(0);            // k-slice 0 in flight (per wave)
  stage(1);            // k-slice 1 in flight
  for (int t = 0; t < nIter; t += 2) {
    // ---- even step: buffer 0, k-slice t ----
    if (t + 1 < nIter) { waitN(); } else { WAITVM0; }   // slice t landed
    __builtin_amdgcn_s_barrier();                       // publish all quarters
    compute(0);
    __builtin_amdgcn_s_barrier();                       // readers done
    if (t + 2 < nIter) stage(0);                        // issue slice t+2
    // ---- odd step: buffer 1, k-slice t+1 ----
    if (t + 2 < nIter) { waitN(); } else { WAITVM0; }   // slice t+1 landed
    __builtin_amdgcn_s_barrier();
    compute(1);
    __builtin_amdgcn_s_barrier();
    if (t + 3 < nIter) stage(1);                        // issue slice t+3
  }

  // epilogue: C/D layout col = lane&15, row = (lane>>4)*4 + reg  [m89/m91]
  const int colb = cb + wc * 32 + lm;
  if (WRITE_PARTIAL) {
    float* Pp = outp + (size_t)blockIdx.z * 2048 * N;
#pragma unroll
    for (int mf = 0; mf < 2; ++mf)
#pragma unroll
      for (int r2 = 0; r2 < 4; ++r2) {
        float* orow =
            Pp + (size_t)(rb + wr * 32 + mf * 16 + kg * 4 + r2) * N + colb;
        orow[0]  = acc[mf][0][r2];
        orow[16] = acc[mf][1][r2];
      }
  } else {
    const float bb0 = bias[colb], bb1 = bias[colb + 16];
#pragma unroll
    for (int mf = 0; mf < 2; ++mf)
#pragma unroll
      for (int r2 = 0; r2 < 4; ++r2) {
        float* orow =
            outp + (size_t)(rb + wr * 32 + mf * 16 + kg * 4 + r2) * N + colb;
        orow[0]  = acc[mf][0][r2] + bb0;
        orow[16] = acc[mf][1][r2] + bb1;
      }
  }
}

// ---------------------------------------------------------------------------
// out = sum_ks P[ks] + bias (fixed order -> deterministic). float4 vectorized.
// ---------------------------------------------------------------------------
__global__ void __launch_bounds__(256) reduce_bias_kernel(
    const float* __restrict__ P, const float* __restrict__ bias,
    float* __restrict__ outp, int MN, int N, int KS) {
  const int idx4 = (blockIdx.x * 256 + threadIdx.x) * 4;
  float4 acc = *(const float4*)&P[idx4];
  for (int ks = 1; ks < KS; ++ks) {
    const float4 p = *(const float4*)&P[(size_t)ks * MN + idx4];
    acc.x += p.x; acc.y += p.y; acc.z += p.z; acc.w += p.w;
  }
  const int col = idx4 % N;
  const float4 b4 = *(const float4*)&bias[col];
  acc.x += b4.x; acc.y += b4.y; acc.z += b4.z; acc.w += b4.w;
  *(float4*)&outp[idx4] = acc;
}

// ---------------------------------------------------------------------------
// S[bh][i][j] = q_i . k_j (fp32). LOWER-TRIANGLE TILES ONLY; j>i masked in
// topk. 64x64x64 tile, 4x4 register tile, operands transposed [d][tok] in LDS.
// ---------------------------------------------------------------------------
__global__ void __launch_bounds__(256) sims_kernel(
    const float* __restrict__ qkv, float* __restrict__ S) {
  const int bh = blockIdx.y;
  const int b = bh / Hc, h = bh % Hc;
  int it = 0;
  {
    const int t = blockIdx.x;
    while ((it + 1) * (it + 2) / 2 <= t) ++it;
  }
  const int jt = blockIdx.x - it * (it + 1) / 2;
  const int tid = threadIdx.x;
  const int tx = tid & 15, ty = tid >> 4;
  __shared__ float Qs[HSc][68];
  __shared__ float Ks[HSc][68];
  const float* base = qkv + (size_t)b * Tc * QKVN + h * HSc;
  {
    const int row = tid >> 2;
    const int d0 = (tid & 3) * 16;
    const float* qrow = base + (size_t)(it * 64 + row) * QKVN;
    const float* krow = base + (size_t)(jt * 64 + row) * QKVN + Cc;
#pragma unroll
    for (int u = 0; u < 4; ++u) {
      const float4 q4 = *(const float4*)&qrow[d0 + u * 4];
      const float4 k4 = *(const float4*)&krow[d0 + u * 4];
      Qs[d0 + u * 4 + 0][row] = q4.x; Qs[d0 + u * 4 + 1][row] = q4.y;
      Qs[d0 + u * 4 + 2][row] = q4.z; Qs[d0 + u * 4 + 3][row] = q4.w;
      Ks[d0 + u * 4 + 0][row] = k4.x; Ks[d0 + u * 4 + 1][row] = k4.y;
      Ks[d0 + u * 4 + 2][row] = k4.z; Ks[d0 + u * 4 + 3][row] = k4.w;
    }
  }
  __syncthreads();
  float acc[4][4];
#pragma unroll
  for (int m = 0; m < 4; ++m)
#pragma unroll
    for (int n = 0; n < 4; ++n) acc[m][n] = 0.0f;
#pragma unroll 4
  for (int d = 0; d < HSc; ++d) {
    const float4 a4 = *(const float4*)&Qs[d][ty * 4];
    const float4 b4 = *(const float4*)&Ks[d][tx * 4];
    const float a[4] = {a4.x, a4.y, a4.z, a4.w};
    const float bv[4] = {b4.x, b4.y, b4.z, b4.w};
#pragma unroll
    for (int m = 0; m < 4; ++m)
#pragma unroll
      for (int n = 0; n < 4; ++n) acc[m][n] += a[m] * bv[n];
  }
  float* Shead = S + (size_t)bh * Tc * Tc;
#pragma unroll
  for (int m = 0; m < 4; ++m) {
    const int i = it * 64 + ty * 4 + m;
    float4 o4 = {acc[m][0], acc[m][1], acc[m][2], acc[m][3]};
    *(float4*)&Shead[(size_t)i * Tc + jt * 64 + tx * 4] = o4;
  }
}

// ---------------------------------------------------------------------------
// Top-16 per token row, one full wave per token. Exact jax.lax.top_k
// semantics. Sort-once + 32-bit tournament (R9, proven); causal-truncated
// loads (R10, proven): lanes with lane*8 > i skip the S load entirely.
// ---------------------------------------------------------------------------
__global__ void __launch_bounds__(256) topk_kernel(
    const float* __restrict__ S, int* __restrict__ topidx,
    unsigned* __restrict__ availB) {
  const int tid = threadIdx.x;
  const int wv = tid >> 6, lane = tid & 63;
  const int tok = blockIdx.x * 4 + wv;  // bh*512 + i
  const int i = tok & (Tc - 1);
  const float4* Sq = reinterpret_cast<const float4*>(S + (size_t)tok * Tc);
  unsigned long long key[8];
#pragma unroll
  for (int r = 0; r < 2; ++r) {
    const int jb = lane * 8 + r * 4;
    if (jb <= i) {  // causal truncation: skip loads entirely beyond i
      const float4 v4 = Sq[lane * 2 + r];
      const float vv[4] = {v4.x, v4.y, v4.z, v4.w};
#pragma unroll
      for (int c = 0; c < 4; ++c) {
        const int j = jb + c;
        const unsigned u = __float_as_uint(vv[c]);
        const unsigned s = (u & 0x80000000u) ? ~u : (u | 0x80000000u);
        key[r * 4 + c] = (j <= i)
            ? (((unsigned long long)s << 32) | (unsigned)(511 - j))
            : 0ull;
      }
    } else {
      key[r * 4 + 0] = 0ull; key[r * 4 + 1] = 0ull;
      key[r * 4 + 2] = 0ull; key[r * 4 + 3] = 0ull;
    }
  }
  // Batcher odd-even mergesort, 8 elems, descending (19 CE, static indices)
#define CE8(a, b)                                                   \
  {                                                                 \
    const unsigned long long lo_ = key[a] < key[b] ? key[a] : key[b]; \
    const unsigned long long hi_ = key[a] < key[b] ? key[b] : key[a]; \
    key[a] = hi_; key[b] = lo_;                                     \
  }
  CE8(0, 1) CE8(2, 3) CE8(0, 2) CE8(1, 3) CE8(1, 2)   // sort4 {0..3}
  CE8(4, 5) CE8(6, 7) CE8(4, 6) CE8(5, 7) CE8(5, 6)   // sort4 {4..7}
  CE8(0, 4) CE8(1, 5) CE8(2, 6) CE8(3, 7)             // odd-even merge
  CE8(2, 4) CE8(3, 5)
  CE8(1, 2) CE8(3, 4) CE8(5, 6)
#undef CE8

  unsigned avail = 0;
#pragma unroll
  for (int m = 0; m < 16; ++m) {
    unsigned g = (unsigned)(key[0] >> 32);  // my head's value part
    const unsigned myhi = g;
#pragma unroll
    for (int msk = 1; msk <= 32; msk <<= 1) {
      const unsigned o = __shfl_xor(g, msk);
      g = o > g ? o : g;
    }
    // ties (equal float value): lowest lane wins == lowest j (exact jax)
    const unsigned long long ball = __ballot(myhi == g);
    const int winner = __ffsll((unsigned long long)ball) - 1;
    const unsigned lo = __shfl((unsigned)key[0], winner);
    const int j = 511 - (int)lo;
    if (lane == 0) topidx[(size_t)tok * 16 + m] = j & 511;
    if (g > 0x007FFFFFu && j != i) avail |= (1u << m);
    if (lane == winner) {  // pop my sorted list (static register shift)
      key[0] = key[1]; key[1] = key[2]; key[2] = key[3]; key[3] = key[4];
      key[4] = key[5]; key[5] = key[6]; key[6] = key[7]; key[7] = 0ull;
    }
  }
  if (lane == 0) availB[tok] = avail;
}

// ---------------------------------------------------------------------------
// Greedy DPP selection, TWO tokens per wave (lanes 0-31 / 32-63), 2 lanes per
// candidate (32 dims each). LOG-FREE scoring (R4, proven). Output y as TWO
// bf16 planes (h,m — proj is 2-plane; l plane dropped).
// ---------------------------------------------------------------------------
__global__ void __launch_bounds__(256, 4) select_kernel(
    const float* __restrict__ qkv, const int* __restrict__ topidx,
    const unsigned* __restrict__ availB, u16* __restrict__ yh,
    u16* __restrict__ ym) {
  const int tid = threadIdx.x;
  const int wv = tid >> 6, lane = tid & 63;
  const int half = lane >> 5;       // which token of the wave's pair
  const int l32 = lane & 31;
  const int m = l32 >> 1;           // candidate 0..15
  const int q = l32 & 1;            // 32-dim half of the 64-dim head
  const int hbase = half << 5;      // shfl base for own half

  const int tok = blockIdx.x * 8 + wv * 2 + half;  // bh*512 + i
  const int bh = tok >> 9;
  const int i = tok & (Tc - 1);
  const int b = bh / Hc;
  const int h = bh % Hc;

  const float* base = qkv + (size_t)b * Tc * QKVN + h * HSc;
  const float* kbase = base + Cc;
  const float* vbase = base + 2 * Cc;

  const int tidx = topidx[(size_t)tok * 16 + m];  // pair-uniform
  unsigned avail = availB[tok];                   // half-uniform

  // gather my candidate's 32-dim slice + k_i's slice into registers
  float kreg[32], kireg[32];
  {
    const float* kc = kbase + (size_t)tidx * QKVN + q * 32;
    const float* ki = kbase + (size_t)i * QKVN + q * 32;
#pragma unroll
    for (int u = 0; u < 8; ++u) {
      const float4 c4 = *(const float4*)&kc[u * 4];
      const float4 i4 = *(const float4*)&ki[u * 4];
      kreg[u * 4 + 0] = c4.x; kreg[u * 4 + 1] = c4.y;
      kreg[u * 4 + 2] = c4.z; kreg[u * 4 + 3] = c4.w;
      kireg[u * 4 + 0] = i4.x; kireg[u * 4 + 1] = i4.y;
      kireg[u * 4 + 2] = i4.z; kireg[u * 4 + 3] = i4.w;
    }
  }
  // fp32 partial dots + pair reduce (shfl_xor 1)
  float cnorm_f = 0.0f, c0_f = 0.0f, kii_f = 0.0f;
#pragma unroll
  for (int e = 0; e < 32; ++e) {
    cnorm_f += kreg[e] * kreg[e];
    c0_f += kreg[e] * kireg[e];
    kii_f += kireg[e] * kireg[e];
  }
  cnorm_f += __shfl_xor(cnorm_f, 1);
  c0_f += __shfl_xor(c0_f, 1);
  kii_f += __shfl_xor(kii_f, 1);

  const double kii = (double)kii_f;
  double z[8];
#pragma unroll
  for (int t = 0; t < 8; ++t) z[t] = 0.0;
  z[0] = (double)c0_f / sqrt(kii);
  double schur = (double)cnorm_f - z[0] * z[0];
  double detS = kii;     // half-uniform
  double Dprev = 0.0;    // accepted D (it=0 bypasses the compare)
  int count = 1;
  int sel[8];
  sel[0] = i;
#pragma unroll
  for (int a = 1; a < 8; ++a) sel[a] = 0;
  bool hdone = false;

  // greedy loop: decisions half-uniform; state updates predicated
#pragma unroll
  for (int it = 0; it < 7; ++it) {
    const double D = detS * schur + EPSd;  // per candidate
    const bool act = ((avail >> m) & 1u) != 0;
    // argmin key: nonpos/NaN D (score NaN/+inf) -> -INF (wins, tie lowest m);
    // unavailable -> +INF (loses)
    const bool bad = !(D > 0.0);
    double dkey = act ? (bad ? -INFINITY : D) : INFINITY;
    int bm = m;
#pragma unroll
    for (int msk = 2; msk <= 16; msk <<= 1) {  // keys pair-replicated
      const double ok2 = __shfl_xor(dkey, msk);
      const int om = __shfl_xor(bm, msk);
      const bool t2 = (ok2 < dkey) || (ok2 == dkey && om < bm);
      dkey = t2 ? ok2 : dkey;
      bm = t2 ? om : bm;
    }
    const double Dbest = __shfl(D, hbase | (bm * 2));  // raw winner D
    bool acc_ok;
    if (it == 0) {
      acc_ok = true;  // MIN_SIZE forces first accept (when avail != 0)
    } else {
      // Dbest^(it+1) < Dprev^(it+2), guarded for nonpos/NaN (-> reject,
      // matching NaN-score semantics of the log form)
      double pA = Dbest, pB = Dprev;
#pragma unroll
      for (int j = 0; j < it; ++j) pA *= Dbest;
#pragma unroll
      for (int j = 0; j < it + 1; ++j) pB *= Dprev;
      acc_ok = ((avail >> bm) & 1u) && (Dbest >= 0.0) && (Dprev >= 0.0) &&
               (pA < pB);
    }
    const bool X = !hdone && (avail != 0u) && acc_ok;
    hdone = hdone || !X;
    if (X) {  // half-uniform branch; shfl sources stay within own half
      // cp = k_c . k_best over this lane's 32 dims
      float cp_f = 0.0f;
#pragma unroll
      for (int e = 0; e < 32; ++e) {
        const float kb = __shfl(kreg[e], hbase | (bm * 2) | q);
        cp_f += kreg[e] * kb;
      }
      cp_f += __shfl_xor(cp_f, 1);
      const double schur_b = __shfl(schur, hbase | (bm * 2));
      double sum = 0.0;
#pragma unroll
      for (int t = 0; t <= it; ++t) {
        const double zbt = __shfl(z[t], hbase | (bm * 2));
        sum += z[t] * zbt;
      }
      const double znew = ((double)cp_f - sum) / sqrt(schur_b);
      z[it + 1] = znew;
      schur -= znew * znew;
      detS *= schur_b;
      Dprev = Dbest;
      avail &= ~(1u << bm);
      ++count;
      sel[it + 1] = __shfl(tidx, hbase | (bm * 2));
    }
    if (__all(hdone)) break;
  }

  // output = mean of selected v rows; each lane handles dims l32 and l32+32
  double acc0 = 0.0, acc1 = 0.0;
#pragma unroll
  for (int a = 0; a < 8; ++a)
    if (a < count) {
      const float* vrow = vbase + (size_t)sel[a] * QKVN;
      acc0 += (double)vrow[l32];
      acc1 += (double)vrow[l32 + 32];
    }
  const float v0 = (float)(acc0 / (double)count);
  const float v1 = (float)(acc1 / (double)count);
  const size_t yidx = (((size_t)b * Tc + i) * Hc + h) * HSc + l32;
  {
    const u16 hv = f2bf(v0);
    yh[yidx] = hv; ym[yidx] = f2bf(v0 - bf2f(hv));
  }
  {
    const u16 hv = f2bf(v1);
    yh[yidx + 32] = hv; ym[yidx + 32] = f2bf(v1 - bf2f(hv));
  }
}

// ---------------------------------------------------------------------------
extern "C" void kernel_launch(void* const* d_in, const int* in_sizes, int n_in,
                              void* d_out, int out_size, void* d_ws, size_t ws_size,
                              hipStream_t stream) {
  (void)in_sizes; (void)n_in; (void)out_size; (void)ws_size;
  const float* x  = (const float*)d_in[0];
  const float* Wa = (const float*)d_in[1];
  const float* ba = (const float*)d_in[2];
  const float* Wp = (const float*)d_in[3];
  const float* bp = (const float*)d_in[4];
  float* out = (float*)d_out;

  constexpr size_t XPLANE = (size_t)Bc * Tc * Cc;      // 1,572,864 elems
  constexpr size_t WAPLANE = (size_t)QKVN * Cc;        // 1,769,472
  constexpr size_t WPPLANE = (size_t)Cc * Cc;          //   589,824

  // Workspace layout (~70.9 MB; region B 50.33 MB time-multiplexed):
  float* qkv = (float*)d_ws;                            // 18.87 MB fp32
  int* topidx = (int*)(qkv + (size_t)Bc * Tc * QKVN);   // 1.57 MB
  unsigned* availB = (unsigned*)(topidx + (size_t)Bc * Hc * Tc * 16);  // 98 KB
  float* regionB = (float*)(availB + (size_t)Bc * Hc * Tc);
  //   phase 1 (pre-sims): X planes (9.44 MB) + W_attn planes (10.6 MB)
  //   phase 2 (sims..topk): S (50.33 MB)
  //   phase 3 (post-topk): Pproj (18.87) + Wp planes (3.54) + y planes (6.3)
  float* S = regionB;
  float* Pproj = regionB;
  u16* Xh = (u16*)regionB;
  u16* Wath = Xh + 3 * XPLANE;
  u16* Wpth = (u16*)(regionB + (size_t)3 * 2048 * Cc);  // past Pproj
  u16* yhp = Wpth + 3 * WPPLANE;                        // past Wp planes

  const int MNproj = Bc * Tc * Cc;   // 1,572,864

  // 1) split X and W_attn into 3 bf16 planes each (W transposed -> [N][K])
  hipLaunchKernelGGL(convsplit3, dim3(1536), dim3(256), 0, stream,
                     x, Xh, Xh + XPLANE, Xh + 2 * XPLANE);
  hipLaunchKernelGGL(convsplit3_t, dim3(12, 36), dim3(256), 0, stream,
                     Wa, Wath, Wath + WAPLANE, Wath + 2 * WAPLANE, Cc, QKVN);
  // 2) qkv = x @ W_attn + b_attn via 3-plane split-bf16 MFMA (identity tile
  //    mapping — R9 geometry)
  hipLaunchKernelGGL((gemm_mfma3<false, 3>), dim3(32, QKVN / 64, 1),
                     dim3(256), 0, stream, Xh, Wath, ba, qkv, QKVN, Cc,
                     (int)XPLANE, (int)WAPLANE);
  // 3) S = Q K^T per head, lower-triangle tiles only (overwrites planes; OK)
  hipLaunchKernelGGL(sims_kernel, dim3(36, Bc * Hc), dim3(256), 0,
                     stream, qkv, S);
  // 4) top-16 per token (sort-once tournament + causal-truncated loads)
  hipLaunchKernelGGL(topk_kernel, dim3(Bc * Hc * Tc / 4), dim3(256), 0,
                     stream, S, topidx, availB);
  // 5) greedy DPP, 2 tokens/wave; writes y as 2 bf16 planes (h,m)
  hipLaunchKernelGGL(select_kernel, dim3(Bc * Hc * Tc / 8), dim3(256), 0,
                     stream, qkv, topidx, availB, yhp, yhp + XPLANE);
  // 6) split W_proj (only h,m planes consumed by 2-plane proj)
  hipLaunchKernelGGL(convsplit3_t, dim3(12, 12), dim3(256), 0, stream,
                     Wp, Wpth, Wpth + WPPLANE, Wpth + 2 * WPPLANE, Cc, Cc);
  // 7) proj partials via 2-PLANE split (no decisions downstream; err ~2^-17)
  hipLaunchKernelGGL((gemm_mfma3<true, 2>), dim3(32, Cc / 64, 3), dim3(256),
                     0, stream, yhp, Wpth, nullptr, Pproj, Cc, 256,
                     (int)XPLANE, (int)WPPLANE);
  hipLaunchKernelGGL(reduce_bias_kernel, dim3(MNproj / 1024), dim3(256), 0,
                     stream, Pproj, bp, out, MNproj, Cc, 3);
}